// Round 5
// baseline (15516.884 us; speedup 1.0000x reference)
//
#include <hip/hip_runtime.h>

#define B_SZ   256
#define T_SZ   128
#define IN_DIM 512
#define EMB    1024
#define HID    1024
#define G4     4096
#define NCLS   10
#define PSTR   2560   // A-plane row stride (shorts): [x 512 | h0 1024 | h1 1024]
#define NBLK   512    // 512 blocks = 2 per CU -> 2 waves/SIMD

typedef __attribute__((ext_vector_type(8))) short short8v;
typedef __attribute__((ext_vector_type(4))) float floatx4;

__device__ __forceinline__ unsigned short bf16hi(float f) {
    union { float f; unsigned u; } v; v.f = f;
    unsigned r = v.u + 0x7fff + ((v.u >> 16) & 1);   // RNE
    return (unsigned short)(r >> 16);
}
__device__ __forceinline__ float bf2f(unsigned short b) {
    union { unsigned u; float f; } v; v.u = ((unsigned)b) << 16;
    return v.f;
}

// ---------------------------------------------------------------------------
// fp32 vector GEMM (setup only): C[M,N] = A[M,K] @ B[K,N]
// ---------------------------------------------------------------------------
template<int BM,int BN,int BK,int TM,int TN>
__global__ __launch_bounds__((BM/TM)*(BN/TN))
void gemm_f32_nn(const float* __restrict__ A, const float* __restrict__ Bm,
                 float* __restrict__ C, int M, int N, int K) {
    constexpr int THREADS = (BM/TM)*(BN/TN);
    __shared__ float As[BK][BM+4];
    __shared__ float Bs[BK][BN+4];
    const int tid  = threadIdx.x;
    const int tcol = tid % (BN/TN);
    const int trow = tid / (BN/TN);
    const int bm   = blockIdx.y * BM;
    const int bn   = blockIdx.x * BN;
    float acc[TM][TN];
#pragma unroll
    for (int i = 0; i < TM; ++i)
#pragma unroll
        for (int j = 0; j < TN; ++j) acc[i][j] = 0.f;
    for (int k0 = 0; k0 < K; k0 += BK) {
#pragma unroll
        for (int r = 0; r < BM*BK/4; r += THREADS) {
            int i  = r + tid;
            int m  = i / (BK/4);
            int kk = (i % (BK/4)) * 4;
            const float4 v = *(const float4*)(&A[(size_t)(bm+m)*K + k0 + kk]);
            As[kk+0][m]=v.x; As[kk+1][m]=v.y; As[kk+2][m]=v.z; As[kk+3][m]=v.w;
        }
#pragma unroll
        for (int r = 0; r < BK*BN/4; r += THREADS) {
            int i  = r + tid;
            int kk = i / (BN/4);
            int n4 = (i % (BN/4)) * 4;
            const float4 v = *(const float4*)(&Bm[(size_t)(k0+kk)*N + bn + n4]);
            *(float4*)(&Bs[kk][n4]) = v;
        }
        __syncthreads();
#pragma unroll
        for (int k = 0; k < BK; ++k) {
            float a[TM], b[TN];
#pragma unroll
            for (int i = 0; i < TM; ++i) a[i] = As[k][trow*TM+i];
#pragma unroll
            for (int j = 0; j < TN; ++j) b[j] = Bs[k][tcol*TN+j];
#pragma unroll
            for (int i = 0; i < TM; ++i)
#pragma unroll
                for (int j = 0; j < TN; ++j) acc[i][j] += a[i]*b[j];
        }
        __syncthreads();
    }
#pragma unroll
    for (int i = 0; i < TM; ++i)
#pragma unroll
        for (int j = 0; j < TN; ++j)
            C[(size_t)(bm+trow*TM+i)*N + bn + tcol*TN + j] = acc[i][j];
}

// ---------------------------------------------------------------------------
// Weight swizzle to frag-major hi/lo, gate-interleaved columns.
// Output col n (0..4095): unit j=n>>2, gate q=n&3 -> source row q*1024 + j.
// K split: kf < kf0 from M0 (width K0), else from M1 (width K1).
// frag (cf, kf): dst[((cf*kfcnt+kf)*2+p)*512 + l*8 + j]
// ---------------------------------------------------------------------------
__global__ void swz2(const float* __restrict__ M0, int K0, int kf0,
                     const float* __restrict__ M1, int K1, int kfcnt,
                     unsigned short* __restrict__ dst) {
    int gid = blockIdx.x * 256 + threadIdx.x;
    int l   = gid & 63;
    int kf  = (gid >> 6) % kfcnt;
    int cf  = gid / (64 * kfcnt);
    int n   = cf*16 + (l & 15);
    int row = ((n & 3) << 10) + (n >> 2);
    const float* src; int kk = (l >> 4) * 8;
    if (kf < kf0) { src = M0 + (size_t)row * K0; kk += kf * 32; }
    else          { src = M1 + (size_t)row * K1; kk += (kf - kf0) * 32; }
    short8v vh, vl;
#pragma unroll
    for (int j = 0; j < 8; ++j) {
        float f = src[kk + j];
        unsigned short h = bf16hi(f);
        vh[j] = (short)h;
        vl[j] = (short)bf16hi(f - bf2f(h));
    }
    size_t base = ((size_t)(cf * kfcnt + kf) * 2) * 512 + (size_t)l * 8;
    *(short8v*)(dst + base)       = vh;
    *(short8v*)(dst + base + 512) = vl;
}

// bcombI[4j+q] = b_ih0 + b_hh0 + W_ih0[row,:] . b_enc   (row = q*1024+j)
__global__ void build_bcombI(const float* __restrict__ W_ih0, const float* __restrict__ b_enc,
                             const float* __restrict__ b_ih0, const float* __restrict__ b_hh0,
                             float* __restrict__ bcombI) {
    int row  = blockIdx.x * 4 + (threadIdx.x >> 6);
    int lane = threadIdx.x & 63;
    const float* w = W_ih0 + (size_t)row * EMB;
    float s = 0.f;
    for (int k = lane; k < EMB; k += 64) s += w[k] * b_enc[k];
#pragma unroll
    for (int o = 32; o > 0; o >>= 1) s += __shfl_down(s, o);
    if (lane == 0) {
        int n = ((row & 1023) << 2) | (row >> 10);
        bcombI[n] = s + b_ih0[row] + b_hh0[row];
    }
}

__global__ void addvI(const float* __restrict__ a, const float* __restrict__ b,
                      float* __restrict__ o) {
    int i = blockIdx.x * 256 + threadIdx.x;
    int n = ((i & 1023) << 2) | (i >> 10);
    o[n] = a[i] + b[i];
}

// ---------------------------------------------------------------------------
// Persistent LSTM kernel. 512 blocks x 256 threads, 2 blocks/CU co-resident.
// Block (rg = bid>>8, cg2 = bid&255): 128-row x 32-col output tile.
//   cg2 < 128 : gates0(t),   A = plane cols 0..1535  (x_t | h0), 48 kf
//   cg2 >= 128: gates1(t-1), A = plane cols 512..2559 (h0 | h1), 64 kf
// Per wave: 64 rows x 16 cols (rowhalf x colhalf), acc[4], 12 MFMA/kf.
// Epilogue: LSTM cell on the block's 8 units x 128 rows; c in registers.
// One grid barrier per phase; planes parity-double-buffered.
// ---------------------------------------------------------------------------
__device__ __forceinline__ void gridbar(unsigned* bar, unsigned target, int tid) {
    __syncthreads();
    if (tid == 0) {
        __threadfence();
        atomicAdd(bar, 1u);
        while (__hip_atomic_load(bar, __ATOMIC_RELAXED, __HIP_MEMORY_SCOPE_AGENT) < target)
            __builtin_amdgcn_s_sleep(1);
        __threadfence();
    }
    __syncthreads();
}

__device__ __forceinline__ void a_load(const unsigned short* __restrict__ ph,
                                       const unsigned short* __restrict__ pl,
                                       int r0, int koff, int sm, int sl,
                                       short8v rh[2], short8v rl[2]) {
#pragma unroll
    for (int q = 0; q < 2; ++q) {
        int ll = sl + q;
        size_t o = (size_t)(r0 + sm*16 + (ll & 15)) * PSTR + koff + ((ll >> 4) * 8);
        rh[q] = *(const short8v*)(ph + o);
        rl[q] = *(const short8v*)(pl + o);
    }
}

__device__ __forceinline__ void a_write(unsigned short (*A)[2][64][8], int sm, int sl,
                                        short8v rh[2], short8v rl[2]) {
#pragma unroll
    for (int q = 0; q < 2; ++q) {
        int ll = sl + q;
        *(short8v*)&A[sm][0][ll][0] = rh[q];
        *(short8v*)&A[sm][1][ll][0] = rl[q];
    }
}

__device__ __forceinline__ void load_b(const unsigned short* bp, int kf,
                                       short8v& bh, short8v& bl) {
    const unsigned short* p = bp + (size_t)kf * 1024;
    bh = *(const short8v*)p;
    bl = *(const short8v*)(p + 512);
}

__device__ __forceinline__ void mfma12(unsigned short (*A)[2][64][8], int rowhalf, int l,
                                       short8v bh, short8v bl, floatx4 (&acc)[4]) {
    short8v ah[4], al[4];
#pragma unroll
    for (int m = 0; m < 4; ++m) {
        ah[m] = *(const short8v*)&A[rowhalf*4 + m][0][l][0];
        al[m] = *(const short8v*)&A[rowhalf*4 + m][1][l][0];
    }
#pragma unroll
    for (int m = 0; m < 4; ++m) {
        acc[m] = __builtin_amdgcn_mfma_f32_16x16x32_bf16(ah[m], bh, acc[m], 0, 0, 0);
        acc[m] = __builtin_amdgcn_mfma_f32_16x16x32_bf16(ah[m], bl, acc[m], 0, 0, 0);
        acc[m] = __builtin_amdgcn_mfma_f32_16x16x32_bf16(al[m], bh, acc[m], 0, 0, 0);
    }
}

__device__ __forceinline__ void store_xz(unsigned short* ph, unsigned short* pl,
                                         int bid, int tid, float2 xv) {
    unsigned short h0 = bf16hi(xv.x), h1 = bf16hi(xv.y);
    ushort2 hh; hh.x = h0; hh.y = h1;
    ushort2 lv; lv.x = bf16hi(xv.x - bf2f(h0)); lv.y = bf16hi(xv.y - bf2f(h1));
    size_t o = (size_t)bid * PSTR + tid * 2;
    *(ushort2*)(ph + o) = hh;
    *(ushort2*)(pl + o) = lv;
}

__global__ __launch_bounds__(256, 2)
void lstm_persist(const float* __restrict__ x,
                  const unsigned short* __restrict__ WLz,
                  const unsigned short* __restrict__ WRz,
                  const float* __restrict__ biasLI, const float* __restrict__ biasRI,
                  unsigned short* __restrict__ p0h, unsigned short* __restrict__ p0l,
                  unsigned short* __restrict__ p1h, unsigned short* __restrict__ p1l,
                  const float* __restrict__ Wcls, const float* __restrict__ bcls,
                  float* __restrict__ out, unsigned* __restrict__ bar) {
    __shared__ unsigned short AslBuf[2][8][2][64][8];   // 32 KB (double-buffered A tile)
    __shared__ float gtile[128][36];                    // 18 KB (pad 36: 2-way = free)

    const int tid = threadIdx.x, bid = blockIdx.x;
    const int w = tid >> 6, l = tid & 63;
    const int rowhalf = w & 1, colhalf = w >> 1;
    const int cg2 = bid & 255, rg = bid >> 8;
    const bool is_left = (cg2 < 128);
    const int r0 = rg * 128;
    const int cgl = is_left ? cg2 : cg2 - 128;
    const int kfcnt = is_left ? 48 : 64;
    const int acol0 = is_left ? 0 : 512;
    const int hcol0 = is_left ? 512 : 1536;
    const int j0 = cgl * 8;
    const unsigned short* Bz = is_left ? WLz : WRz;
    const float* biasI = is_left ? biasLI : biasRI;
    const int sm = tid >> 5, sl = (tid & 31) * 2;

    unsigned short* PH[2] = {p0h, p1h};
    unsigned short* PL[2] = {p0l, p1l};

    const int cf0 = cgl * 2 + colhalf;
    const unsigned short* bp = Bz + ((size_t)cf0 * kfcnt) * 1024 + (size_t)l * 8;

    float biasv;
    { int cA = cgl*32 + colhalf*16 + (l & 15);
      biasv = biasI[cA]; }

    float cst[4];
#pragma unroll
    for (int i = 0; i < 4; ++i) cst[i] = 0.f;

    unsigned target = 0;

    // prologue: stage x(0) into plane 0
    if (bid < B_SZ) {
        float2 xv = *(const float2*)&x[((size_t)bid * T_SZ) * IN_DIM + tid * 2];
        store_xz(p0h, p0l, bid, tid, xv);
    }
    target += NBLK; gridbar(bar, target, tid);

    for (int t = 0; t <= T_SZ; ++t) {
        const int cur = t & 1, nxt = cur ^ 1;
        const bool conv = (t < T_SZ - 1) && (bid < B_SZ);
        float2 xv;
        if (conv) xv = *(const float2*)&x[((size_t)bid * T_SZ + t + 1) * IN_DIM + tid * 2];

        const bool active = is_left ? (t < T_SZ) : (t >= 1);
        if (active) {
            const unsigned short* ph = PH[cur];
            const unsigned short* plo = PL[cur];

            floatx4 acc[4];
#pragma unroll
            for (int m = 0; m < 4; ++m) acc[m] = (floatx4){biasv, biasv, biasv, biasv};

            short8v rh[2], rl[2];
            short8v b0h, b0l, b1h, b1l;

            a_load(ph, plo, r0, acol0, sm, sl, rh, rl);
            a_write(&AslBuf[0][0], sm, sl, rh, rl);
            load_b(bp, 0, b0h, b0l);
            load_b(bp, 1, b1h, b1l);
            __syncthreads();

            for (int kf2 = 0; kf2 < kfcnt; kf2 += 2) {
                // kf = kf2 (reads buf 0, writes buf 1)
                a_load(ph, plo, r0, acol0 + (kf2+1)*32, sm, sl, rh, rl);
                mfma12(&AslBuf[0][0], rowhalf, l, b0h, b0l, acc);
                if (kf2 + 2 < kfcnt) load_b(bp, kf2+2, b0h, b0l);
                a_write(&AslBuf[1][0], sm, sl, rh, rl);
                __syncthreads();
                // kf = kf2+1 (reads buf 1, writes buf 0)
                if (kf2 + 2 < kfcnt) a_load(ph, plo, r0, acol0 + (kf2+2)*32, sm, sl, rh, rl);
                mfma12(&AslBuf[1][0], rowhalf, l, b1h, b1l, acc);
                if (kf2 + 3 < kfcnt) load_b(bp, kf2+3, b1h, b1l);
                if (kf2 + 2 < kfcnt) a_write(&AslBuf[0][0], sm, sl, rh, rl);
                __syncthreads();
            }

            // write gates to LDS tile (bias already seeded in acc)
#pragma unroll
            for (int m = 0; m < 4; ++m) {
                int col = colhalf*16 + (l & 15);
#pragma unroll
                for (int jj = 0; jj < 4; ++jj)
                    gtile[rowhalf*64 + m*16 + ((l >> 4)*4) + jj][col] = acc[m][jj];
            }
            __syncthreads();

            // LSTM cell on 8 units x 128 rows (4 cells/thread), c in regs
            {
                int u = tid & 7, rq = tid >> 3;
                unsigned short* nh = PH[nxt];
                unsigned short* nl = PL[nxt];
#pragma unroll
                for (int i = 0; i < 4; ++i) {
                    int r = rq*4 + i;
                    float4 gq = *(const float4*)&gtile[r][4*u];
                    float ii = 1.f / (1.f + expf(-gq.x));
                    float ff = 1.f / (1.f + expf(-gq.y));
                    float gg = tanhf(gq.z);
                    float oo = 1.f / (1.f + expf(-gq.w));
                    float cn = ff * cst[i] + ii * gg;
                    cst[i] = cn;
                    float h = oo * tanhf(cn);
                    unsigned short hh = bf16hi(h);
                    size_t o = (size_t)(r0 + r) * PSTR + hcol0 + j0 + u;
                    nh[o] = hh;
                    nl[o] = bf16hi(h - bf2f(hh));
                }
            }
        }

        if (conv) store_xz(PH[nxt], PL[nxt], bid, tid, xv);
        target += NBLK; gridbar(bar, target, tid);
    }

    // classifier: block bid (<256) -> batch row bid; h1 = plane[(T+1)&1] cols 1536..2559
    if (bid < B_SZ) {
        const unsigned short* hh = PH[(T_SZ + 1) & 1];
        const unsigned short* hl = PL[(T_SZ + 1) & 1];
        float part[NCLS];
#pragma unroll
        for (int n = 0; n < NCLS; ++n) part[n] = 0.f;
        for (int k = tid; k < HID; k += 256) {
            size_t o = (size_t)bid * PSTR + 1536 + k;
            float hv = bf2f(hh[o]) + bf2f(hl[o]);
#pragma unroll
            for (int n = 0; n < NCLS; ++n) part[n] += hv * Wcls[(size_t)n * HID + k];
        }
        float* red = (float*)gtile;
        for (int n = 0; n < NCLS; ++n) {
            red[tid] = part[n];
            __syncthreads();
            for (int s = 128; s > 0; s >>= 1) {
                if (tid < s) red[tid] += red[tid + s];
                __syncthreads();
            }
            if (tid == 0) out[(size_t)bid * NCLS + n] = red[0] + bcls[n];
            __syncthreads();
        }
    }
}

extern "C" void kernel_launch(void* const* d_in, const int* in_sizes, int n_in,
                              void* d_out, int out_size, void* d_ws, size_t ws_size,
                              hipStream_t stream) {
    const float* x      = (const float*)d_in[0];
    const float* W_enc  = (const float*)d_in[1];
    const float* b_enc  = (const float*)d_in[2];
    const float* W_ih0  = (const float*)d_in[3];
    const float* W_hh0  = (const float*)d_in[4];
    const float* b_ih0  = (const float*)d_in[5];
    const float* b_hh0  = (const float*)d_in[6];
    const float* W_ih1  = (const float*)d_in[7];
    const float* W_hh1  = (const float*)d_in[8];
    const float* b_ih1  = (const float*)d_in[9];
    const float* b_hh1  = (const float*)d_in[10];
    const float* W_cls  = (const float*)d_in[11];
    const float* b_cls  = (const float*)d_in[12];
    float* out = (float*)d_out;

    float* ws = (float*)d_ws;
    size_t off = 0;
    unsigned short* WLz    = (unsigned short*)(ws + off); off += (size_t)G4 * 1536 * 2 / 2;
    unsigned short* WRz    = (unsigned short*)(ws + off); off += (size_t)G4 * 2048 * 2 / 2;
    float*          Wcomb  = ws + off;                    off += (size_t)G4 * IN_DIM;
    float*          biasLI = ws + off;                    off += G4;
    float*          biasRI = ws + off;                    off += G4;
    unsigned short* planes = (unsigned short*)(ws + off); off += (size_t)4 * B_SZ * PSTR / 2;
    unsigned*       bar    = (unsigned*)(ws + off);       off += 64;

    unsigned short* p0h = planes;
    unsigned short* p0l = p0h + (size_t)B_SZ * PSTR;
    unsigned short* p1h = p0l + (size_t)B_SZ * PSTR;
    unsigned short* p1l = p1h + (size_t)B_SZ * PSTR;

    // --- setup ---
    gemm_f32_nn<128,128,16,8,8><<<dim3(IN_DIM/128, G4/128), 256, 0, stream>>>(
        W_ih0, W_enc, Wcomb, G4, IN_DIM, EMB);
    build_bcombI<<<G4/4, 256, 0, stream>>>(W_ih0, b_enc, b_ih0, b_hh0, biasLI);
    addvI<<<G4/256, 256, 0, stream>>>(b_ih1, b_hh1, biasRI);
    // WLz: [Wcomb(16 kf) | W_hh0(32 kf)] ; WRz: [W_ih1(32 kf) | W_hh1(32 kf)]
    swz2<<<64*48, 256, 0, stream>>>(Wcomb, IN_DIM, 16, W_hh0, HID, 48, WLz);
    swz2<<<64*64, 256, 0, stream>>>(W_ih1, HID, 32, W_hh1, HID, 64, WRz);
    hipMemsetAsync(planes, 0, (size_t)4 * B_SZ * PSTR * 2, stream);
    hipMemsetAsync(bar, 0, sizeof(unsigned), stream);

    // --- the whole recurrence in one kernel ---
    lstm_persist<<<NBLK, 256, 0, stream>>>(
        x, WLz, WRz, biasLI, biasRI,
        p0h, p0l, p1h, p1l, W_cls, b_cls, out, bar);
}

// Round 6
// 8384.292 us; speedup vs baseline: 1.8507x; 1.8507x over previous
//
#include <hip/hip_runtime.h>

#define B_SZ   256
#define T_SZ   128
#define IN_DIM 512
#define EMB    1024
#define HID    1024
#define G4     4096
#define NCLS   10
#define PSTR   2560   // A-plane row stride (shorts): [x 512 | h0 1024 | h1 1024]
#define NBLK   256    // 256 blocks x 512 threads (8 waves), 1 block/CU

typedef __attribute__((ext_vector_type(8))) short short8v;
typedef __attribute__((ext_vector_type(4))) float floatx4;

__device__ __forceinline__ unsigned short bf16hi(float f) {
    union { float f; unsigned u; } v; v.f = f;
    unsigned r = v.u + 0x7fff + ((v.u >> 16) & 1);   // RNE
    return (unsigned short)(r >> 16);
}
__device__ __forceinline__ float bf2f(unsigned short b) {
    union { unsigned u; float f; } v; v.u = ((unsigned)b) << 16;
    return v.f;
}

// ---------------------------------------------------------------------------
// fp32 vector GEMM (setup only): C[M,N] = A[M,K] @ B[K,N]
// ---------------------------------------------------------------------------
template<int BM,int BN,int BK,int TM,int TN>
__global__ __launch_bounds__((BM/TM)*(BN/TN))
void gemm_f32_nn(const float* __restrict__ A, const float* __restrict__ Bm,
                 float* __restrict__ C, int M, int N, int K) {
    constexpr int THREADS = (BM/TM)*(BN/TN);
    __shared__ float As[BK][BM+4];
    __shared__ float Bs[BK][BN+4];
    const int tid  = threadIdx.x;
    const int tcol = tid % (BN/TN);
    const int trow = tid / (BN/TN);
    const int bm   = blockIdx.y * BM;
    const int bn   = blockIdx.x * BN;
    float acc[TM][TN];
#pragma unroll
    for (int i = 0; i < TM; ++i)
#pragma unroll
        for (int j = 0; j < TN; ++j) acc[i][j] = 0.f;
    for (int k0 = 0; k0 < K; k0 += BK) {
#pragma unroll
        for (int r = 0; r < BM*BK/4; r += THREADS) {
            int i  = r + tid;
            int m  = i / (BK/4);
            int kk = (i % (BK/4)) * 4;
            const float4 v = *(const float4*)(&A[(size_t)(bm+m)*K + k0 + kk]);
            As[kk+0][m]=v.x; As[kk+1][m]=v.y; As[kk+2][m]=v.z; As[kk+3][m]=v.w;
        }
#pragma unroll
        for (int r = 0; r < BK*BN/4; r += THREADS) {
            int i  = r + tid;
            int kk = i / (BN/4);
            int n4 = (i % (BN/4)) * 4;
            const float4 v = *(const float4*)(&Bm[(size_t)(k0+kk)*N + bn + n4]);
            *(float4*)(&Bs[kk][n4]) = v;
        }
        __syncthreads();
#pragma unroll
        for (int k = 0; k < BK; ++k) {
            float a[TM], b[TN];
#pragma unroll
            for (int i = 0; i < TM; ++i) a[i] = As[k][trow*TM+i];
#pragma unroll
            for (int j = 0; j < TN; ++j) b[j] = Bs[k][tcol*TN+j];
#pragma unroll
            for (int i = 0; i < TM; ++i)
#pragma unroll
                for (int j = 0; j < TN; ++j) acc[i][j] += a[i]*b[j];
        }
        __syncthreads();
    }
#pragma unroll
    for (int i = 0; i < TM; ++i)
#pragma unroll
        for (int j = 0; j < TN; ++j)
            C[(size_t)(bm+trow*TM+i)*N + bn + tcol*TN + j] = acc[i][j];
}

// ---------------------------------------------------------------------------
// Weight swizzle to frag-major hi/lo, gate-interleaved columns.
// Output col n (0..4095): unit j=n>>2, gate q=n&3 -> source row q*1024 + j.
// K split: kf < kf0 from M0 (width K0), else from M1 (width K1).
// frag (cf, kf): dst[((cf*kfcnt+kf)*2+p)*512 + l*8 + j]
// ---------------------------------------------------------------------------
__global__ void swz2(const float* __restrict__ M0, int K0, int kf0,
                     const float* __restrict__ M1, int K1, int kfcnt,
                     unsigned short* __restrict__ dst) {
    int gid = blockIdx.x * 256 + threadIdx.x;
    int l   = gid & 63;
    int kf  = (gid >> 6) % kfcnt;
    int cf  = gid / (64 * kfcnt);
    int n   = cf*16 + (l & 15);
    int row = ((n & 3) << 10) + (n >> 2);
    const float* src; int kk = (l >> 4) * 8;
    if (kf < kf0) { src = M0 + (size_t)row * K0; kk += kf * 32; }
    else          { src = M1 + (size_t)row * K1; kk += (kf - kf0) * 32; }
    short8v vh, vl;
#pragma unroll
    for (int j = 0; j < 8; ++j) {
        float f = src[kk + j];
        unsigned short h = bf16hi(f);
        vh[j] = (short)h;
        vl[j] = (short)bf16hi(f - bf2f(h));
    }
    size_t base = ((size_t)(cf * kfcnt + kf) * 2) * 512 + (size_t)l * 8;
    *(short8v*)(dst + base)       = vh;
    *(short8v*)(dst + base + 512) = vl;
}

// bcombI[4j+q] = b_ih0 + b_hh0 + W_ih0[row,:] . b_enc   (row = q*1024+j)
__global__ void build_bcombI(const float* __restrict__ W_ih0, const float* __restrict__ b_enc,
                             const float* __restrict__ b_ih0, const float* __restrict__ b_hh0,
                             float* __restrict__ bcombI) {
    int row  = blockIdx.x * 4 + (threadIdx.x >> 6);
    int lane = threadIdx.x & 63;
    const float* w = W_ih0 + (size_t)row * EMB;
    float s = 0.f;
    for (int k = lane; k < EMB; k += 64) s += w[k] * b_enc[k];
#pragma unroll
    for (int o = 32; o > 0; o >>= 1) s += __shfl_down(s, o);
    if (lane == 0) {
        int n = ((row & 1023) << 2) | (row >> 10);
        bcombI[n] = s + b_ih0[row] + b_hh0[row];
    }
}

__global__ void addvI(const float* __restrict__ a, const float* __restrict__ b,
                      float* __restrict__ o) {
    int i = blockIdx.x * 256 + threadIdx.x;
    int n = ((i & 1023) << 2) | (i >> 10);
    o[n] = a[i] + b[i];
}

// ---------------------------------------------------------------------------
// Persistent LSTM kernel. 256 blocks x 512 threads (8 waves), 1 block/CU.
// Block (rg = bid>>7, cg = bid&127): 128-row x 64-col output tile.
//   cg < 64  : gates0(t),   A = plane cols 0..1535  (x_t | h0), 48 kf
//   cg >= 64 : gates1(t-1), A = plane cols 512..2559 (h0 | h1), 64 kf
// 8 waves = 2 K-groups x (2 rowhalf x 2 colhalf). Each K-group does SMAX=kf/2
// slices; partials summed via gtile. Wave = 64 rows x 32 cols, acc[4][2].
// Staging: per slice, 32 x 1KB fragments; wave w reg-stages segs w*4..w*4+3
// (lane-linear ds_write_b128, conflict-free), loads issued 2 slices ahead.
// One grid barrier per phase; planes parity-double-buffered.
// ---------------------------------------------------------------------------
__device__ __forceinline__ void gridbar(unsigned* bar, unsigned target, int tid) {
    __syncthreads();
    if (tid == 0) {
        __threadfence();
        atomicAdd(bar, 1u);
        while (__hip_atomic_load(bar, __ATOMIC_RELAXED, __HIP_MEMORY_SCOPE_AGENT) < target)
            __builtin_amdgcn_s_sleep(1);
        __threadfence();
    }
    __syncthreads();
}

__device__ __forceinline__ void load_b(const unsigned short* bp0, const unsigned short* bp1, int kf,
                                       short8v& h0, short8v& l0, short8v& h1, short8v& l1) {
    const unsigned short* p0 = bp0 + (size_t)kf * 1024;
    const unsigned short* p1 = bp1 + (size_t)kf * 1024;
    h0 = *(const short8v*)p0; l0 = *(const short8v*)(p0 + 512);
    h1 = *(const short8v*)p1; l1 = *(const short8v*)(p1 + 512);
}

__device__ __forceinline__ void mfma24(const unsigned short (*A)[2][64][8], int rowhalf, int l,
                                       short8v bh0, short8v bl0, short8v bh1, short8v bl1,
                                       floatx4 (&acc)[4][2]) {
    short8v ah[4], al[4];
#pragma unroll
    for (int m = 0; m < 4; ++m) {
        ah[m] = *(const short8v*)&A[rowhalf*4 + m][0][l][0];
        al[m] = *(const short8v*)&A[rowhalf*4 + m][1][l][0];
    }
#pragma unroll
    for (int m = 0; m < 4; ++m) {
        acc[m][0] = __builtin_amdgcn_mfma_f32_16x16x32_bf16(ah[m], bh0, acc[m][0], 0, 0, 0);
        acc[m][0] = __builtin_amdgcn_mfma_f32_16x16x32_bf16(ah[m], bl0, acc[m][0], 0, 0, 0);
        acc[m][0] = __builtin_amdgcn_mfma_f32_16x16x32_bf16(al[m], bh0, acc[m][0], 0, 0, 0);
        acc[m][1] = __builtin_amdgcn_mfma_f32_16x16x32_bf16(ah[m], bh1, acc[m][1], 0, 0, 0);
        acc[m][1] = __builtin_amdgcn_mfma_f32_16x16x32_bf16(ah[m], bl1, acc[m][1], 0, 0, 0);
        acc[m][1] = __builtin_amdgcn_mfma_f32_16x16x32_bf16(al[m], bh1, acc[m][1], 0, 0, 0);
    }
}

__device__ __forceinline__ void store_xz(unsigned short* ph, unsigned short* pl,
                                         int bid, int tid, float2 xv) {
    unsigned short h0 = bf16hi(xv.x), h1 = bf16hi(xv.y);
    ushort2 hh; hh.x = h0; hh.y = h1;
    ushort2 lv; lv.x = bf16hi(xv.x - bf2f(h0)); lv.y = bf16hi(xv.y - bf2f(h1));
    size_t o = (size_t)bid * PSTR + tid * 2;
    *(ushort2*)(ph + o) = hh;
    *(ushort2*)(pl + o) = lv;
}

typedef unsigned short AslT[2][8][2][64][8];   // [buf][mf][pl][lane][8] per k-group

__global__ __launch_bounds__(512, 1)
void lstm_persist(const float* __restrict__ x,
                  const unsigned short* __restrict__ WLz,
                  const unsigned short* __restrict__ WRz,
                  const float* __restrict__ biasLI, const float* __restrict__ biasRI,
                  unsigned short* __restrict__ p0h, unsigned short* __restrict__ p0l,
                  unsigned short* __restrict__ p1h, unsigned short* __restrict__ p1l,
                  const float* __restrict__ Wcls, const float* __restrict__ bcls,
                  float* __restrict__ out, unsigned* __restrict__ bar) {
    __shared__ unsigned char smem[65536];            // Asl[2 grp] (64 KB) ∪ gtile (34.8 KB)
    AslT*  Asl   = (AslT*)smem;                      // Asl[g][buf][mf][pl][64][8]
    float (*gtile)[68] = (float (*)[68])smem;        // [128][68]

    const int tid = threadIdx.x, bid = blockIdx.x;
    const int w = tid >> 6, l = tid & 63;
    const int kgrp = w >> 2, sub = w & 3;
    const int rowhalf = sub & 1, colhalf = sub >> 1;
    const int cg = bid & 127, rg = bid >> 7;
    const bool is_left = (cg < 64);
    const int cgl = is_left ? cg : cg - 64;
    const int SMAX = is_left ? 24 : 32;              // kf per K-group
    const int kfcnt = 2 * SMAX;
    const int acol0 = is_left ? 0 : 512;
    const int hcol0 = is_left ? 512 : 1536;
    const int r0 = rg * 128;
    const unsigned short* Bz = is_left ? WLz : WRz;
    const float* biasI = is_left ? biasLI : biasRI;

    // B fragment pointers: wave covers cols colhalf*32..+31 => cf = cgl*4+colhalf*2+{0,1}
    const int cf0 = cgl*4 + colhalf*2;
    const unsigned short* bp0 = Bz + ((size_t)cf0     * kfcnt) * 1024 + (size_t)l * 8;
    const unsigned short* bp1 = Bz + ((size_t)(cf0+1) * kfcnt) * 1024 + (size_t)l * 8;
    const int kbase = kgrp * SMAX;

    float bias0 = 0.f, bias1 = 0.f;
    if (kgrp == 0) {
        int cA = cgl*64 + colhalf*32 + (l & 15);
        bias0 = biasI[cA]; bias1 = biasI[cA + 16];
    }

    unsigned short* PH[2] = {p0h, p1h};
    unsigned short* PL[2] = {p0l, p1l};

    float cst[4];
#pragma unroll
    for (int i = 0; i < 4; ++i) cst[i] = 0.f;

    unsigned target = 0;

    if (tid < 256) {   // stage x(0) into plane 0 (bid == batch row)
        float2 xv = *(const float2*)&x[((size_t)bid * T_SZ) * IN_DIM + tid * 2];
        store_xz(p0h, p0l, bid, tid, xv);
    }
    target += NBLK; gridbar(bar, target, tid);

    for (int t = 0; t <= T_SZ; ++t) {
        const int cur = t & 1, nxt = cur ^ 1;
        const bool conv = (t < T_SZ - 1) && (tid < 256);
        float2 xv;
        if (conv) xv = *(const float2*)&x[((size_t)bid * T_SZ + t + 1) * IN_DIM + tid * 2];

        const bool active = is_left ? (t < T_SZ) : (t >= 1);
        if (active) {
            const unsigned short* ph  = PH[cur];
            const unsigned short* plo = PL[cur];

            floatx4 acc[4][2];
#pragma unroll
            for (int m = 0; m < 4; ++m) {
                acc[m][0] = (floatx4){bias0, bias0, bias0, bias0};
                acc[m][1] = (floatx4){bias1, bias1, bias1, bias1};
            }

            short8v sreg[4];
            // wave w stages segs w*4+i: g=seg>>4, mf=(seg>>1)&7, pl=seg&1
            auto stage_load = [&](int s1) {
#pragma unroll
                for (int i = 0; i < 4; ++i) {
                    int seg = w*4 + i;
                    int g = seg >> 4, mf = (seg >> 1) & 7, pl = seg & 1;
                    const unsigned short* p = pl ? plo : ph;
                    size_t o = (size_t)(r0 + mf*16 + (l & 15)) * PSTR
                             + acol0 + (g*SMAX + s1)*32 + ((l >> 4) * 8);
                    sreg[i] = *(const short8v*)(p + o);
                }
            };
            auto stage_write = [&](int b) {
#pragma unroll
                for (int i = 0; i < 4; ++i) {
                    int seg = w*4 + i;
                    int g = seg >> 4, mf = (seg >> 1) & 7, pl = seg & 1;
                    *(short8v*)&Asl[g][b][mf][pl][l][0] = sreg[i];
                }
            };

            short8v bAh0,bAl0,bAh1,bAl1, bBh0,bBl0,bBh1,bBl1;

            stage_load(0); stage_write(0);
            load_b(bp0, bp1, kbase + 0, bAh0, bAl0, bAh1, bAl1);
            load_b(bp0, bp1, kbase + 1, bBh0, bBl0, bBh1, bBl1);
            stage_load(1);
            __syncthreads();

            for (int s2 = 0; s2 < SMAX; s2 += 2) {
                // slice s2: compute buf0; write R(s2+1)->buf1; load R(s2+2)
                if (s2 + 1 < SMAX) stage_write(1);
                if (s2 + 2 < SMAX) stage_load(s2 + 2);
                mfma24((const unsigned short (*)[2][64][8])Asl[kgrp][0],
                       rowhalf, l, bAh0, bAl0, bAh1, bAl1, acc);
                if (s2 + 2 < SMAX) load_b(bp0, bp1, kbase + s2 + 2, bAh0, bAl0, bAh1, bAl1);
                __syncthreads();
                // slice s2+1: compute buf1; write R(s2+2)->buf0; load R(s2+3)
                if (s2 + 2 < SMAX) stage_write(0);
                if (s2 + 3 < SMAX) stage_load(s2 + 3);
                if (s2 + 1 < SMAX)
                    mfma24((const unsigned short (*)[2][64][8])Asl[kgrp][1],
                           rowhalf, l, bBh0, bBl0, bBh1, bBl1, acc);
                if (s2 + 3 < SMAX) load_b(bp0, bp1, kbase + s2 + 3, bBh0, bBl0, bBh1, bBl1);
                __syncthreads();
            }

            // partial-sum reduction: group0 writes, group1 adds
            if (kgrp == 0) {
#pragma unroll
                for (int m = 0; m < 4; ++m)
#pragma unroll
                    for (int c = 0; c < 2; ++c) {
                        int col = colhalf*32 + c*16 + (l & 15);
#pragma unroll
                        for (int jj = 0; jj < 4; ++jj)
                            gtile[rowhalf*64 + m*16 + ((l >> 4)*4) + jj][col] = acc[m][c][jj];
                    }
            }
            __syncthreads();
            if (kgrp == 1) {
#pragma unroll
                for (int m = 0; m < 4; ++m)
#pragma unroll
                    for (int c = 0; c < 2; ++c) {
                        int col = colhalf*32 + c*16 + (l & 15);
#pragma unroll
                        for (int jj = 0; jj < 4; ++jj)
                            gtile[rowhalf*64 + m*16 + ((l >> 4)*4) + jj][col] += acc[m][c][jj];
                    }
            }
            __syncthreads();

            // LSTM cell: 16 units x 128 rows, 4 cells/thread, c-state in regs
            {
                int u = tid & 15, rq = tid >> 4;
                unsigned short* nh = PH[nxt];
                unsigned short* nl = PL[nxt];
#pragma unroll
                for (int i = 0; i < 4; ++i) {
                    int r = rq*4 + i;
                    float4 gq = *(const float4*)&gtile[r][4*u];
                    float ii = 1.f / (1.f + expf(-gq.x));
                    float ff = 1.f / (1.f + expf(-gq.y));
                    float gg = tanhf(gq.z);
                    float oo = 1.f / (1.f + expf(-gq.w));
                    float cn = ff * cst[i] + ii * gg;
                    cst[i] = cn;
                    float h = oo * tanhf(cn);
                    unsigned short hh = bf16hi(h);
                    size_t o = (size_t)(r0 + r) * PSTR + hcol0 + cgl*16 + u;
                    nh[o] = hh;
                    nl[o] = bf16hi(h - bf2f(hh));
                }
            }
        }

        if (conv) store_xz(PH[nxt], PL[nxt], bid, tid, xv);
        target += NBLK; gridbar(bar, target, tid);
    }

    // classifier: block bid -> batch row bid; h1 = plane[(T+1)&1] cols 1536..2559
    {
        const unsigned short* hh = PH[(T_SZ + 1) & 1];
        const unsigned short* hl = PL[(T_SZ + 1) & 1];
        float part[NCLS];
#pragma unroll
        for (int n = 0; n < NCLS; ++n) part[n] = 0.f;
        for (int k = tid; k < HID; k += 512) {
            size_t o = (size_t)bid * PSTR + 1536 + k;
            float hv = bf2f(hh[o]) + bf2f(hl[o]);
#pragma unroll
            for (int n = 0; n < NCLS; ++n) part[n] += hv * Wcls[(size_t)n * HID + k];
        }
        float* red = (float*)smem;
        for (int n = 0; n < NCLS; ++n) {
            red[tid] = part[n];
            __syncthreads();
            for (int s = 256; s > 0; s >>= 1) {
                if (tid < s) red[tid] += red[tid + s];
                __syncthreads();
            }
            if (tid == 0) out[(size_t)bid * NCLS + n] = red[0] + bcls[n];
            __syncthreads();
        }
    }
}

extern "C" void kernel_launch(void* const* d_in, const int* in_sizes, int n_in,
                              void* d_out, int out_size, void* d_ws, size_t ws_size,
                              hipStream_t stream) {
    const float* x      = (const float*)d_in[0];
    const float* W_enc  = (const float*)d_in[1];
    const float* b_enc  = (const float*)d_in[2];
    const float* W_ih0  = (const float*)d_in[3];
    const float* W_hh0  = (const float*)d_in[4];
    const float* b_ih0  = (const float*)d_in[5];
    const float* b_hh0  = (const float*)d_in[6];
    const float* W_ih1  = (const float*)d_in[7];
    const float* W_hh1  = (const float*)d_in[8];
    const float* b_ih1  = (const float*)d_in[9];
    const float* b_hh1  = (const float*)d_in[10];
    const float* W_cls  = (const float*)d_in[11];
    const float* b_cls  = (const float*)d_in[12];
    float* out = (float*)d_out;

    float* ws = (float*)d_ws;
    size_t off = 0;
    unsigned short* WLz    = (unsigned short*)(ws + off); off += (size_t)G4 * 1536 * 2 / 2;
    unsigned short* WRz    = (unsigned short*)(ws + off); off += (size_t)G4 * 2048 * 2 / 2;
    float*          Wcomb  = ws + off;                    off += (size_t)G4 * IN_DIM;
    float*          biasLI = ws + off;                    off += G4;
    float*          biasRI = ws + off;                    off += G4;
    unsigned short* planes = (unsigned short*)(ws + off); off += (size_t)4 * B_SZ * PSTR / 2;
    unsigned*       bar    = (unsigned*)(ws + off);       off += 64;

    unsigned short* p0h = planes;
    unsigned short* p0l = p0h + (size_t)B_SZ * PSTR;
    unsigned short* p1h = p0l + (size_t)B_SZ * PSTR;
    unsigned short* p1l = p1h + (size_t)B_SZ * PSTR;

    // --- setup ---
    gemm_f32_nn<128,128,16,8,8><<<dim3(IN_DIM/128, G4/128), 256, 0, stream>>>(
        W_ih0, W_enc, Wcomb, G4, IN_DIM, EMB);
    build_bcombI<<<G4/4, 256, 0, stream>>>(W_ih0, b_enc, b_ih0, b_hh0, biasLI);
    addvI<<<G4/256, 256, 0, stream>>>(b_ih1, b_hh1, biasRI);
    // WLz: [Wcomb(16 kf) | W_hh0(32 kf)] ; WRz: [W_ih1(32 kf) | W_hh1(32 kf)]
    swz2<<<64*48, 256, 0, stream>>>(Wcomb, IN_DIM, 16, W_hh0, HID, 48, WLz);
    swz2<<<64*64, 256, 0, stream>>>(W_ih1, HID, 32, W_hh1, HID, 64, WRz);
    hipMemsetAsync(planes, 0, (size_t)4 * B_SZ * PSTR * 2, stream);
    hipMemsetAsync(bar, 0, sizeof(unsigned), stream);

    // --- the whole recurrence in one kernel ---
    lstm_persist<<<NBLK, 512, 0, stream>>>(
        x, WLz, WRz, biasLI, biasRI,
        p0h, p0l, p1h, p1l, W_cls, b_cls, out, bar);
}